// Round 7
// baseline (359.403 us; speedup 1.0000x reference)
//
#include <hip/hip_runtime.h>
#include <math.h>

#define D 128
#define B_SZ 1024
#define KNB 200
#define AW 392    // Ah LDS stride (halves)
#define SCW 1028  // scores LDS stride (f32)
#define PW 1032   // P LDS stride (halves)

typedef _Float16 half8 __attribute__((ext_vector_type(8)));
typedef _Float16 half4 __attribute__((ext_vector_type(4)));
typedef float floatx4 __attribute__((ext_vector_type(4)));

__device__ __forceinline__ float sigmoid_f(float x) { return 1.f / (1.f + __expf(-x)); }
__device__ __forceinline__ float tanh_fast(float x) { return 1.f - 2.f / (__expf(2.f * x) + 1.f); }

// ---------------------------------------------------------------------------
// Kernel P: stream the embedding table sequentially to populate Infinity
// Cache (L3) before the random gather. Block-sum to scratch defeats DCE.
// ---------------------------------------------------------------------------
__global__ __launch_bounds__(256) void k_prefetch(
    const float4* __restrict__ emb4, int n4, float* __restrict__ scratch)
{
    float s = 0.f;
    for (int i = blockIdx.x * 256 + threadIdx.x; i < n4; i += gridDim.x * 256) {
        float4 v = emb4[i];
        s += v.x + v.y + v.z + v.w;
    }
    for (int off = 32; off; off >>= 1) s += __shfl_down(s, off);
    if ((threadIdx.x & 63) == 0) scratch[blockIdx.x * 4 + (threadIdx.x >> 6)] = s;
}

// ---------------------------------------------------------------------------
// Kernel 0: one-time fp16 LSTM weights, unified [1024][384]:
// row u = [w_ih[u,0:128] | w_hh[u,0:256]]. 192 blocks x 256 thr.
// ---------------------------------------------------------------------------
__global__ __launch_bounds__(256) void k_cvtw(
    const float* __restrict__ w_ih, const float* __restrict__ w_hh,
    _Float16* __restrict__ w16)
{
    const int i8 = (blockIdx.x * 256 + threadIdx.x) * 8;
    const int row = i8 / 384, k = i8 % 384;
    const float* src = (k < 128) ? &w_ih[row * 128 + k] : &w_hh[row * 256 + (k - 128)];
    float4 v0 = *(const float4*)src;
    float4 v1 = *(const float4*)(src + 4);
    half8 h;
    h[0] = (_Float16)v0.x; h[1] = (_Float16)v0.y; h[2] = (_Float16)v0.z; h[3] = (_Float16)v0.w;
    h[4] = (_Float16)v1.x; h[5] = (_Float16)v1.y; h[6] = (_Float16)v1.z; h[7] = (_Float16)v1.w;
    *(half8*)&w16[i8] = h;
}

// ---------------------------------------------------------------------------
// Kernel 1: gather+sum, GCN linear, support encoder, query gather.
// One block per batch row b, 512 threads.
// ---------------------------------------------------------------------------
__global__ __launch_bounds__(512) void k_support(
    const int* __restrict__ relations, const int* __restrict__ entities,
    const int* __restrict__ query, const float* __restrict__ emb,
    const float* __restrict__ gcn_w, const float* __restrict__ gcn_b,
    const float* __restrict__ p1_w, const float* __restrict__ p1_b,
    const float* __restrict__ p2_w, const float* __restrict__ p2_b,
    const float* __restrict__ ln_a, const float* __restrict__ ln_b,
    float* __restrict__ sg, _Float16* __restrict__ sgH, _Float16* __restrict__ sgT,
    _Float16* __restrict__ qbH)
{
    __shared__ int idxs[2 * KNB];
    __shared__ __align__(16) float part[16][132];
    __shared__ __align__(16) float S[2 * D];
    __shared__ __align__(16) float sup[D];
    __shared__ __align__(16) float hid[2 * D];
    __shared__ __align__(16) float zv[D];
    __shared__ float red2[2];

    const int b = blockIdx.x;
    const int t = threadIdx.x;

    if (t < KNB) idxs[t] = relations[b * KNB + t];
    else if (t < 2 * KNB) idxs[t] = entities[b * KNB + (t - KNB)];
    __syncthreads();

    {
        const int g = t >> 5, c4 = (t & 31) * 4;
        const int* mi = &idxs[(g >> 3) * KNB];
        float4 a4 = make_float4(0.f, 0.f, 0.f, 0.f);
        #pragma unroll 5
        for (int k = (g & 7); k < KNB; k += 8) {
            float4 v = *(const float4*)&emb[(size_t)mi[k] * D + c4];
            a4.x += v.x; a4.y += v.y; a4.z += v.z; a4.w += v.w;
        }
        *(float4*)&part[g][c4] = a4;
    }
    __syncthreads();
    if (t < 2 * D) {
        const int half = t >> 7, c = t & 127;
        float s = 0.f;
        #pragma unroll
        for (int j = 0; j < 8; ++j) s += part[half * 8 + j][c];
        S[t] = s;
    }
    __syncthreads();

    if (t < D) {
        const float4* w4 = (const float4*)(gcn_w + t * 2 * D);
        float dot = 0.f;
        #pragma unroll 8
        for (int f = 0; f < 2 * D / 4; ++f) {
            float4 w = w4[f];
            float4 s = *(const float4*)&S[f * 4];
            dot += w.x * s.x + w.y * s.y + w.z * s.z + w.w * s.w;
        }
        float v = (dot + 200.f * gcn_b[t]) * (1.f / 1024.f);  // num_neighbors = B = 1024
        sup[t] = tanhf(v);
    }
    __syncthreads();

    if (t < 2 * D) {
        const float4* w4 = (const float4*)(p1_w + t * D);
        float dot = 0.f;
        #pragma unroll 8
        for (int f = 0; f < D / 4; ++f) {
            float4 w = w4[f];
            float4 s = *(const float4*)&sup[f * 4];
            dot += w.x * s.x + w.y * s.y + w.z * s.z + w.w * s.w;
        }
        float h = dot + p1_b[t];
        hid[t] = h > 0.f ? h : 0.f;
    }
    __syncthreads();

    if (t < D) {
        const float4* w4 = (const float4*)(p2_w + t * 2 * D);
        float dot = 0.f;
        #pragma unroll 8
        for (int f = 0; f < 2 * D / 4; ++f) {
            float4 w = w4[f];
            float4 s = *(const float4*)&hid[f * 4];
            dot += w.x * s.x + w.y * s.y + w.z * s.z + w.w * s.w;
        }
        zv[t] = dot + p2_b[t] + sup[t];
    }
    __syncthreads();

    if (t < 64) {
        float x0 = zv[t], x1 = zv[t + 64];
        float s = x0 + x1;
        for (int off = 32; off; off >>= 1) s += __shfl_down(s, off);
        float mu = __shfl(s, 0) * (1.f / 128.f);
        float d0 = x0 - mu, d1 = x1 - mu;
        float v = d0 * d0 + d1 * d1;
        for (int off = 32; off; off >>= 1) v += __shfl_down(v, off);
        v = __shfl(v, 0);
        if (t == 0) { red2[0] = mu; red2[1] = sqrtf(v * (1.f / 127.f)); }
    }
    __syncthreads();
    if (t < D) {
        float mu = red2[0], sigma = red2[1];
        float val = (zv[t] - mu) / (sigma + 1e-3f) * ln_a[t] + ln_b[t];
        sg[b * D + t] = val;
        sgH[b * D + t] = (_Float16)val;
        sgT[t * B_SZ + b] = (_Float16)val;
        qbH[b * D + t] = (_Float16)emb[(size_t)query[b] * D + t];
    }
}

// ---------------------------------------------------------------------------
// Kernel 2: FUSED 4-step LSTM+attention chain + cosine.
// 64 blocks x 16 rows, 1024 threads (16 waves, 4/SIMD).
// Wave wv: gate-units wv*16..+16 (all 4 gates); 4 score j-tiles; r-GEMM as
// (n-tile = wv&7, K-half = wv>>3) with LDS combine. Softmax: wave wv -> row wv.
// g_q = q@w_ih^T cached in registers across steps.
// ---------------------------------------------------------------------------
__global__ __launch_bounds__(1024) void k_chain(
    const _Float16* __restrict__ qbH, const _Float16* __restrict__ sgH,
    const _Float16* __restrict__ sgT, const float* __restrict__ sg,
    const _Float16* __restrict__ w16, const float* __restrict__ b_ih,
    const float* __restrict__ b_hh, float* __restrict__ out)
{
    __shared__ _Float16 Ah[16 * AW];      // [16][392]: 0:128 q | 128:256 h | 256:384 r
    __shared__ float    Sc[16 * SCW];     // scores f32
    __shared__ _Float16 P[16 * PW];       // exp(s - mx), unscaled
    __shared__ float    sinv[16];
    __shared__ float    rpar[2][16][132]; // r split-K partials
    __shared__ float    hsave[16][132];   // final h_out f32

    const int t = threadIdx.x;
    const int wv = t >> 6, lane = t & 63;
    const int m = lane & 15, quad = lane >> 4;
    const int b0 = blockIdx.x * 16;

    // stage q rows into Ah[:, 0:128]
    if (t < 256) {
        const int row = t >> 4, ch = (t & 15) * 8;
        *(half8*)&Ah[row * AW + ch] = *(const half8*)&qbH[(b0 + row) * D + ch];
    }

    // bias: wave wv's 16 units, 4 gates
    const int unit = wv * 16 + m;
    float bi[4];
    #pragma unroll
    for (int g = 0; g < 4; ++g) bi[g] = b_ih[g * 256 + unit] + b_hh[g * 256 + unit];

    floatx4 cfr;
    floatx4 gq[4];
    floatx4 acc[4];
    #pragma unroll
    for (int i = 0; i < 4; ++i) cfr[i] = 0.f;
    #pragma unroll
    for (int g = 0; g < 4; ++g)
        #pragma unroll
        for (int i = 0; i < 4; ++i) gq[g][i] = 0.f;

    __syncthreads();

    // ---- g_q = q @ w_ih^T  (K=128), cached across all steps
    #pragma unroll
    for (int ks = 0; ks < 4; ++ks) {
        half8 a = *(const half8*)&Ah[m * AW + ks * 32 + quad * 8];
        #pragma unroll
        for (int g = 0; g < 4; ++g) {
            half8 bf = *(const half8*)&w16[(g * 256 + unit) * 384 + ks * 32 + quad * 8];
            gq[g] = __builtin_amdgcn_mfma_f32_16x16x32_f16(a, bf, gq[g], 0, 0, 0);
        }
    }

    auto gates_hr = [&]() {  // acc = gq + h_r @ w_hh^T  (K=256)
        #pragma unroll
        for (int g = 0; g < 4; ++g) acc[g] = gq[g];
        #pragma unroll
        for (int ks = 0; ks < 8; ++ks) {
            half8 a = *(const half8*)&Ah[m * AW + 128 + ks * 32 + quad * 8];
            #pragma unroll
            for (int g = 0; g < 4; ++g) {
                half8 bf = *(const half8*)&w16[(g * 256 + unit) * 384 + 128 + ks * 32 + quad * 8];
                acc[g] = __builtin_amdgcn_mfma_f32_16x16x32_f16(a, bf, acc[g], 0, 0, 0);
            }
        }
    };

    auto pointwise = [&](bool first, bool save) {
        __syncthreads();  // all waves done reading Ah h-slice before overwrite
        #pragma unroll
        for (int rr = 0; rr < 4; ++rr) {
            float gi = acc[0][rr] + bi[0];
            float gf = acc[1][rr] + bi[1];
            float gg = acc[2][rr] + bi[2];
            float go = acc[3][rr] + bi[3];
            float cold = first ? 0.f : cfr[rr];
            float cn = sigmoid_f(gf) * cold + sigmoid_f(gi) * tanh_fast(gg);
            cfr[rr] = cn;
            if (wv < 8) {  // units 0..127 -> h_out
                const int row = quad * 4 + rr;
                float qv = (float)Ah[row * AW + unit];
                float ho = qv + sigmoid_f(go) * tanh_fast(cn);
                Ah[row * AW + 128 + unit] = (_Float16)ho;
                if (save) hsave[row][unit] = ho;
            }
        }
    };

    auto attn = [&]() {
        __syncthreads();  // h writes visible
        // scores: wave wv -> j-tiles wv*4 .. wv*4+3
        #pragma unroll
        for (int i = 0; i < 4; ++i) {
            const int j0 = (wv * 4 + i) * 16;
            floatx4 a2;
            #pragma unroll
            for (int z = 0; z < 4; ++z) a2[z] = 0.f;
            #pragma unroll
            for (int ks = 0; ks < 4; ++ks) {
                half8 a = *(const half8*)&Ah[m * AW + 128 + ks * 32 + quad * 8];
                half8 bf = *(const half8*)&sgH[(j0 + m) * D + ks * 32 + quad * 8];
                a2 = __builtin_amdgcn_mfma_f32_16x16x32_f16(a, bf, a2, 0, 0, 0);
            }
            #pragma unroll
            for (int rr = 0; rr < 4; ++rr)
                Sc[(quad * 4 + rr) * SCW + j0 + m] = a2[rr];
        }
        __syncthreads();
        // softmax: wave wv owns row wv entirely (64 lanes x 16 cols)
        {
            const int row = wv;
            float vals[16];
            float mm = -1e30f;
            #pragma unroll
            for (int j = 0; j < 16; ++j) {
                vals[j] = Sc[row * SCW + lane + j * 64];
                mm = fmaxf(mm, vals[j]);
            }
            #pragma unroll
            for (int off = 32; off; off >>= 1) mm = fmaxf(mm, __shfl_down(mm, off));
            mm = __shfl(mm, 0);
            float ss = 0.f;
            #pragma unroll
            for (int j = 0; j < 16; ++j) {
                float e = __expf(vals[j] - mm);
                P[row * PW + lane + j * 64] = (_Float16)e;
                ss += e;
            }
            #pragma unroll
            for (int off = 32; off; off >>= 1) ss += __shfl_down(ss, off);
            if (lane == 0) sinv[row] = 1.f / ss;
        }
        __syncthreads();
        // r partials: wave -> (n-tile = wv&7, K-half = wv>>3), 16-deep chain
        {
            const int nt = wv & 7, kh = wv >> 3;
            floatx4 a3;
            #pragma unroll
            for (int z = 0; z < 4; ++z) a3[z] = 0.f;
            #pragma unroll
            for (int ks = 0; ks < 16; ++ks) {
                const int kk = kh * 16 + ks;
                half8 a = *(const half8*)&P[m * PW + kk * 32 + quad * 8];
                half8 bf = *(const half8*)&sgT[(nt * 16 + m) * B_SZ + kk * 32 + quad * 8];
                a3 = __builtin_amdgcn_mfma_f32_16x16x32_f16(a, bf, a3, 0, 0, 0);
            }
            #pragma unroll
            for (int rr = 0; rr < 4; ++rr)
                rpar[kh][quad * 4 + rr][nt * 16 + m] = a3[rr];
        }
        __syncthreads();
        // combine K-halves, scale by 1/sum, write r-slice of Ah
        #pragma unroll
        for (int e = t; e < 2048; e += 1024) {
            const int row = e >> 7, col = e & 127;
            float v = (rpar[0][row][col] + rpar[1][row][col]) * sinv[row];
            Ah[row * AW + 256 + col] = (_Float16)v;
        }
        __syncthreads();
    };

    // ---- step 0: gates = g_q + bias (h_r == 0)
    #pragma unroll
    for (int g = 0; g < 4; ++g) acc[g] = gq[g];
    pointwise(true, false);
    attn();
    // ---- steps 1..2
    gates_hr(); pointwise(false, false); attn();
    gates_hr(); pointwise(false, false); attn();
    // ---- step 3 (attention dead)
    gates_hr(); pointwise(false, true);

    __syncthreads();
    // cosine: wave 0; row = t&15, part = t>>4 (4 parts x 32 cols)
    if (t < 64) {
        const int row = t & 15, part = t >> 4;
        float cr = 0.f, n1 = 0.f, n2 = 0.f;
        #pragma unroll 8
        for (int j = 0; j < 32; ++j) {
            const int c = part * 32 + j;
            float h = hsave[row][c];
            float s = sg[(b0 + row) * D + c];
            cr += h * s; n1 += h * h; n2 += s * s;
        }
        cr += __shfl_down(cr, 16); n1 += __shfl_down(n1, 16); n2 += __shfl_down(n2, 16);
        cr += __shfl_down(cr, 32); n1 += __shfl_down(n1, 32); n2 += __shfl_down(n2, 32);
        if (t < 16) out[b0 + row] = cr / sqrtf(n1 * n2);
    }
}

// ---------------------------------------------------------------------------
extern "C" void kernel_launch(void* const* d_in, const int* in_sizes, int n_in,
                              void* d_out, int out_size, void* d_ws, size_t ws_size,
                              hipStream_t stream)
{
    const int*   relations = (const int*)d_in[0];
    const int*   entities  = (const int*)d_in[1];
    const int*   query     = (const int*)d_in[2];
    const float* emb       = (const float*)d_in[3];
    const float* gcn_w     = (const float*)d_in[4];
    const float* gcn_b     = (const float*)d_in[5];
    const float* p1_w      = (const float*)d_in[6];
    const float* p1_b      = (const float*)d_in[7];
    const float* p2_w      = (const float*)d_in[8];
    const float* p2_b      = (const float*)d_in[9];
    const float* ln_a      = (const float*)d_in[10];
    const float* ln_b      = (const float*)d_in[11];
    const float* w_ih      = (const float*)d_in[12];
    const float* w_hh      = (const float*)d_in[13];
    const float* b_ih      = (const float*)d_in[14];
    const float* b_hh      = (const float*)d_in[15];

    // Workspace (float-slot offsets; fp16 1024x128 buffers = 65536 slots each)
    float* ws = (float*)d_ws;
    float*     sg      = ws;                          // 131072
    _Float16*  sgH     = (_Float16*)(ws + 131072);    // 65536
    _Float16*  sgT     = (_Float16*)(ws + 196608);    // 65536
    _Float16*  qbH     = (_Float16*)(ws + 262144);    // 65536
    _Float16*  w16     = (_Float16*)(ws + 327680);    // 196608 slots
    float*     scratch = ws + 524288;                 // 8192
    // end: 532480 floats = 2.13 MB

    const int n4 = (200001 * D) / 4;
    k_prefetch<<<dim3(2048), dim3(256), 0, stream>>>((const float4*)emb, n4, scratch);
    k_cvtw<<<dim3(192), dim3(256), 0, stream>>>(w_ih, w_hh, w16);
    k_support<<<dim3(B_SZ), dim3(512), 0, stream>>>(
        relations, entities, query, emb, gcn_w, gcn_b,
        p1_w, p1_b, p2_w, p2_b, ln_a, ln_b, sg, sgH, sgT, qbH);
    k_chain<<<dim3(64), dim3(1024), 0, stream>>>(
        qbH, sgH, sgT, sg, w16, b_ih, b_hh, (float*)d_out);
}

// Round 8
// 304.858 us; speedup vs baseline: 1.1789x; 1.1789x over previous
//
#include <hip/hip_runtime.h>
#include <math.h>

#define D 128
#define B_SZ 1024
#define KNB 200
#define AWQ 136   // q LDS stride (halves) in k_gq      (68 dw %32=4 -> 2-way, free)
#define AWG 264   // [h|r] LDS stride (halves) in gates (132 dw %32=4 -> 2-way, free)
#define HW 136    // h LDS stride (halves) in attn
#define SCW 1028  // scores LDS stride (f32)
#define PW 1048   // P LDS stride (halves) (524 dw %32=12 -> 2-way pairs)

typedef _Float16 half8 __attribute__((ext_vector_type(8)));
typedef _Float16 half4 __attribute__((ext_vector_type(4)));
typedef float floatx4 __attribute__((ext_vector_type(4)));

__device__ __forceinline__ float sigmoid_f(float x) { return 1.f / (1.f + __expf(-x)); }
__device__ __forceinline__ float tanh_fast(float x) { return 1.f - 2.f / (__expf(2.f * x) + 1.f); }

// ---------------------------------------------------------------------------
// Kernel 0: one-time fp16 LSTM weights (split layout):
// w16[0:131072] = w_ih [1024][128]; w16[131072:] = w_hh [1024][256].
// ---------------------------------------------------------------------------
__global__ __launch_bounds__(256) void k_cvtw(
    const float* __restrict__ w_ih, const float* __restrict__ w_hh,
    _Float16* __restrict__ w16)
{
    const int i8 = (blockIdx.x * 256 + threadIdx.x) * 8;
    const float* src = (i8 < 131072) ? (w_ih + i8) : (w_hh + (i8 - 131072));
    float4 v0 = *(const float4*)src;
    float4 v1 = *(const float4*)(src + 4);
    half8 h;
    h[0] = (_Float16)v0.x; h[1] = (_Float16)v0.y; h[2] = (_Float16)v0.z; h[3] = (_Float16)v0.w;
    h[4] = (_Float16)v1.x; h[5] = (_Float16)v1.y; h[6] = (_Float16)v1.z; h[7] = (_Float16)v1.w;
    *(half8*)&w16[i8] = h;
}

// ---------------------------------------------------------------------------
// Kernel 1: gather+sum, GCN linear, support encoder, query gather.
// One block per batch row b, 512 threads. (Known wall: ~1.25 TB/s random.)
// ---------------------------------------------------------------------------
__global__ __launch_bounds__(512) void k_support(
    const int* __restrict__ relations, const int* __restrict__ entities,
    const int* __restrict__ query, const float* __restrict__ emb,
    const float* __restrict__ gcn_w, const float* __restrict__ gcn_b,
    const float* __restrict__ p1_w, const float* __restrict__ p1_b,
    const float* __restrict__ p2_w, const float* __restrict__ p2_b,
    const float* __restrict__ ln_a, const float* __restrict__ ln_b,
    float* __restrict__ sg, _Float16* __restrict__ sgH, _Float16* __restrict__ sgT,
    float* __restrict__ qb, _Float16* __restrict__ qbH)
{
    __shared__ int idxs[2 * KNB];
    __shared__ __align__(16) float part[16][132];
    __shared__ __align__(16) float S[2 * D];
    __shared__ __align__(16) float sup[D];
    __shared__ __align__(16) float hid[2 * D];
    __shared__ __align__(16) float zv[D];
    __shared__ float red2[2];

    const int b = blockIdx.x;
    const int t = threadIdx.x;

    if (t < KNB) idxs[t] = relations[b * KNB + t];
    else if (t < 2 * KNB) idxs[t] = entities[b * KNB + (t - KNB)];
    __syncthreads();

    {
        const int g = t >> 5, c4 = (t & 31) * 4;
        const int* mi = &idxs[(g >> 3) * KNB];
        float4 a4 = make_float4(0.f, 0.f, 0.f, 0.f);
        #pragma unroll 5
        for (int k = (g & 7); k < KNB; k += 8) {
            float4 v = *(const float4*)&emb[(size_t)mi[k] * D + c4];
            a4.x += v.x; a4.y += v.y; a4.z += v.z; a4.w += v.w;
        }
        *(float4*)&part[g][c4] = a4;
    }
    __syncthreads();
    if (t < 2 * D) {
        const int half = t >> 7, c = t & 127;
        float s = 0.f;
        #pragma unroll
        for (int j = 0; j < 8; ++j) s += part[half * 8 + j][c];
        S[t] = s;
    }
    __syncthreads();

    if (t < D) {
        const float4* w4 = (const float4*)(gcn_w + t * 2 * D);
        float dot = 0.f;
        #pragma unroll 8
        for (int f = 0; f < 2 * D / 4; ++f) {
            float4 w = w4[f];
            float4 s = *(const float4*)&S[f * 4];
            dot += w.x * s.x + w.y * s.y + w.z * s.z + w.w * s.w;
        }
        float v = (dot + 200.f * gcn_b[t]) * (1.f / 1024.f);  // num_neighbors = B = 1024
        sup[t] = tanhf(v);
    }
    __syncthreads();

    if (t < 2 * D) {
        const float4* w4 = (const float4*)(p1_w + t * D);
        float dot = 0.f;
        #pragma unroll 8
        for (int f = 0; f < D / 4; ++f) {
            float4 w = w4[f];
            float4 s = *(const float4*)&sup[f * 4];
            dot += w.x * s.x + w.y * s.y + w.z * s.z + w.w * s.w;
        }
        float h = dot + p1_b[t];
        hid[t] = h > 0.f ? h : 0.f;
    }
    __syncthreads();

    if (t < D) {
        const float4* w4 = (const float4*)(p2_w + t * 2 * D);
        float dot = 0.f;
        #pragma unroll 8
        for (int f = 0; f < 2 * D / 4; ++f) {
            float4 w = w4[f];
            float4 s = *(const float4*)&hid[f * 4];
            dot += w.x * s.x + w.y * s.y + w.z * s.z + w.w * s.w;
        }
        zv[t] = dot + p2_b[t] + sup[t];
    }
    __syncthreads();

    if (t < 64) {
        float x0 = zv[t], x1 = zv[t + 64];
        float s = x0 + x1;
        for (int off = 32; off; off >>= 1) s += __shfl_down(s, off);
        float mu = __shfl(s, 0) * (1.f / 128.f);
        float d0 = x0 - mu, d1 = x1 - mu;
        float v = d0 * d0 + d1 * d1;
        for (int off = 32; off; off >>= 1) v += __shfl_down(v, off);
        v = __shfl(v, 0);
        if (t == 0) { red2[0] = mu; red2[1] = sqrtf(v * (1.f / 127.f)); }
    }
    __syncthreads();
    if (t < D) {
        float mu = red2[0], sigma = red2[1];
        float val = (zv[t] - mu) / (sigma + 1e-3f) * ln_a[t] + ln_b[t];
        sg[b * D + t] = val;
        sgH[b * D + t] = (_Float16)val;
        sgT[t * B_SZ + b] = (_Float16)val;
        float qv = emb[(size_t)query[b] * D + t];
        qb[b * D + t] = qv;
        qbH[b * D + t] = (_Float16)qv;
    }
}

// ---------------------------------------------------------------------------
// Kernel 2: gq = q @ w_ih^T (raw, pre-bias, stored f32) + step-0 LSTM
// pointwise (c=0). Grid (16,16), 256 threads (4 waves x 16 rows).
// ---------------------------------------------------------------------------
__global__ __launch_bounds__(256) void k_gq(
    const _Float16* __restrict__ qbH, const _Float16* __restrict__ w16,
    const float* __restrict__ b_ih, const float* __restrict__ b_hh,
    const float* __restrict__ qb, float* __restrict__ gqB,
    float* __restrict__ cbuf, float* __restrict__ hout, _Float16* __restrict__ houtH)
{
    __shared__ _Float16 Ah[64 * AWQ];
    __shared__ _Float16 Bh[2][4][16][40];

    const int t = threadIdx.x;
    const int b0 = blockIdx.x * 64;
    const int n0 = blockIdx.y * 16;
    const int lane = t & 63, wv = t >> 6;
    const int m = lane & 15, quad = lane >> 4;

    {   // stage q (fp16 copies)
        const int row = t >> 2, gr = b0 + row;
        #pragma unroll
        for (int i = 0; i < 4; ++i) {
            const int c = (t & 3) * 8 + i * 32;
            *(half8*)&Ah[row * AWQ + c] = *(const half8*)&qbH[gr * D + c];
        }
    }
    const int sg_g = t >> 6, sg_u = (t >> 2) & 15, sg_kq = (t & 3) * 8;
    auto stage_b = [&](int ks, int buf) {
        const int grow = sg_g * 256 + n0 + sg_u;
        *(half8*)&Bh[buf][sg_g][sg_u][sg_kq] = *(const half8*)&w16[grow * D + ks * 32 + sg_kq];
    };
    stage_b(0, 0);
    __syncthreads();

    floatx4 acc[4];
    #pragma unroll
    for (int g = 0; g < 4; ++g)
        #pragma unroll
        for (int i = 0; i < 4; ++i) acc[g][i] = 0.f;

    for (int ks = 0; ks < 4; ++ks) {
        if (ks + 1 < 4) stage_b(ks + 1, (ks + 1) & 1);
        half8 a = *(const half8*)&Ah[(wv * 16 + m) * AWQ + ks * 32 + quad * 8];
        #pragma unroll
        for (int g = 0; g < 4; ++g) {
            half8 bf = *(const half8*)&Bh[ks & 1][g][m][quad * 8];
            acc[g] = __builtin_amdgcn_mfma_f32_16x16x32_f16(a, bf, acc[g], 0, 0, 0);
        }
        __syncthreads();
    }

    const int unit = n0 + m;
    float bi[4];
    #pragma unroll
    for (int g = 0; g < 4; ++g) bi[g] = b_ih[g * 256 + unit] + b_hh[g * 256 + unit];
    #pragma unroll
    for (int rr = 0; rr < 4; ++rr) {
        const int b = b0 + wv * 16 + quad * 4 + rr;
        // store raw gq for steps 1-3
        #pragma unroll
        for (int g = 0; g < 4; ++g) gqB[(size_t)b * 1024 + g * 256 + unit] = acc[g][rr];
        // step-0 pointwise (c = 0)
        float gi = acc[0][rr] + bi[0];
        float gg = acc[2][rr] + bi[2];
        float go = acc[3][rr] + bi[3];
        float cn = sigmoid_f(gi) * tanh_fast(gg);
        cbuf[b * 256 + unit] = cn;
        if (n0 < D) {
            float ho = qb[b * D + unit] + sigmoid_f(go) * tanh_fast(cn);
            hout[b * D + unit] = ho;
            houtH[b * D + unit] = (_Float16)ho;
        }
    }
}

// ---------------------------------------------------------------------------
// Kernel 3: FUSED attention: scores = h@sg^T -> softmax -> r = P@sg (fp16 out).
// 64 blocks x 16 rows, 1024 threads (16 waves). One phase each.
// ---------------------------------------------------------------------------
__global__ __launch_bounds__(1024) void k_attn(
    const _Float16* __restrict__ hH, const _Float16* __restrict__ sgH,
    const _Float16* __restrict__ sgT, _Float16* __restrict__ rH)
{
    __shared__ _Float16 Hh[16 * HW];
    __shared__ float    Sc[16 * SCW];
    __shared__ _Float16 P[16 * PW];
    __shared__ float    sinv[16];
    __shared__ float    rpar[2][16][132];

    const int t = threadIdx.x;
    const int wv = t >> 6, lane = t & 63;
    const int m = lane & 15, quad = lane >> 4;
    const int b0 = blockIdx.x * 16;

    if (t < 256) {
        const int row = t >> 4, c = (t & 15) * 8;
        *(half8*)&Hh[row * HW + c] = *(const half8*)&hH[(b0 + row) * D + c];
    }
    __syncthreads();

    // ---- scores: wave wv -> j-tiles wv*4..+3 (4 independent acc chains)
    {
        floatx4 a2[4];
        #pragma unroll
        for (int i = 0; i < 4; ++i)
            #pragma unroll
            for (int z = 0; z < 4; ++z) a2[i][z] = 0.f;
        #pragma unroll
        for (int ks = 0; ks < 4; ++ks) {
            half8 a = *(const half8*)&Hh[m * HW + ks * 32 + quad * 8];
            #pragma unroll
            for (int i = 0; i < 4; ++i) {
                const int j0 = (wv * 4 + i) * 16;
                half8 bf = *(const half8*)&sgH[(j0 + m) * D + ks * 32 + quad * 8];
                a2[i] = __builtin_amdgcn_mfma_f32_16x16x32_f16(a, bf, a2[i], 0, 0, 0);
            }
        }
        #pragma unroll
        for (int i = 0; i < 4; ++i) {
            const int j0 = (wv * 4 + i) * 16;
            #pragma unroll
            for (int rr = 0; rr < 4; ++rr)
                Sc[(quad * 4 + rr) * SCW + j0 + m] = a2[i][rr];
        }
    }
    __syncthreads();

    // ---- softmax: wave wv owns row wv (64 lanes x 16 cols)
    {
        const int row = wv;
        float vals[16];
        float mm = -1e30f;
        #pragma unroll
        for (int j = 0; j < 16; ++j) {
            vals[j] = Sc[row * SCW + lane + j * 64];
            mm = fmaxf(mm, vals[j]);
        }
        #pragma unroll
        for (int off = 32; off; off >>= 1) mm = fmaxf(mm, __shfl_down(mm, off));
        mm = __shfl(mm, 0);
        float ss = 0.f;
        #pragma unroll
        for (int j = 0; j < 16; ++j) {
            float e = __expf(vals[j] - mm);
            P[row * PW + lane + j * 64] = (_Float16)e;
            ss += e;
        }
        #pragma unroll
        for (int off = 32; off; off >>= 1) ss += __shfl_down(ss, off);
        if (lane == 0) sinv[row] = 1.f / ss;
    }
    __syncthreads();

    // ---- r partials: wave -> (n-tile = wv&7, K-half = wv>>3)
    {
        const int nt = wv & 7, kh = wv >> 3;
        floatx4 a3;
        #pragma unroll
        for (int z = 0; z < 4; ++z) a3[z] = 0.f;
        #pragma unroll
        for (int ks = 0; ks < 16; ++ks) {
            const int kk = kh * 16 + ks;
            half8 a = *(const half8*)&P[m * PW + kk * 32 + quad * 8];
            half8 bf = *(const half8*)&sgT[(nt * 16 + m) * B_SZ + kk * 32 + quad * 8];
            a3 = __builtin_amdgcn_mfma_f32_16x16x32_f16(a, bf, a3, 0, 0, 0);
        }
        #pragma unroll
        for (int rr = 0; rr < 4; ++rr)
            rpar[kh][quad * 4 + rr][nt * 16 + m] = a3[rr];
    }
    __syncthreads();

    // ---- combine + scale -> rH
    if (t < 2048) {
        const int e = t;
        const int row = e >> 7, col = e & 127;
        float v = (rpar[0][row][col] + rpar[1][row][col]) * sinv[row];
        rH[(b0 + row) * D + col] = (_Float16)v;
    }
    if (t >= 1024 - 1024 + 1024) {}  // no-op
    {
        const int e = t + 1024;
        if (e < 2048) {
            const int row = e >> 7, col = e & 127;
            float v = (rpar[0][row][col] + rpar[1][row][col]) * sinv[row];
            rH[(b0 + row) * D + col] = (_Float16)v;
        }
    }
}

// ---------------------------------------------------------------------------
// Kernel 4: gates step s>=1: acc = gq + [h|r] @ w_hh^T (K=256) + pointwise.
// Grid (16,16), 256 threads.
// ---------------------------------------------------------------------------
__global__ __launch_bounds__(256) void k_gates(
    const _Float16* __restrict__ hHin, const _Float16* __restrict__ rH,
    const _Float16* __restrict__ w16, const float* __restrict__ gqB,
    const float* __restrict__ b_ih, const float* __restrict__ b_hh,
    const float* __restrict__ qb, float* __restrict__ cbuf,
    float* __restrict__ hout, _Float16* __restrict__ hHout)
{
    __shared__ _Float16 Ah[64 * AWG];
    __shared__ _Float16 Bh[2][4][16][40];

    const int t = threadIdx.x;
    const int b0 = blockIdx.x * 64;
    const int n0 = blockIdx.y * 16;
    const int lane = t & 63, wv = t >> 6;
    const int m = lane & 15, quad = lane >> 4;

    {   // stage [h|r] (pure fp16 copies)
        const int row = t >> 2, gr = b0 + row;
        #pragma unroll
        for (int i = 0; i < 8; ++i) {
            const int c = (t & 3) * 8 + i * 32;
            half8 h;
            if (c < 128) h = *(const half8*)&hHin[gr * D + c];
            else         h = *(const half8*)&rH[gr * D + (c - 128)];
            *(half8*)&Ah[row * AWG + c] = h;
        }
    }
    const int sg_g = t >> 6, sg_u = (t >> 2) & 15, sg_kq = (t & 3) * 8;
    auto stage_b = [&](int ks, int buf) {
        const int grow = sg_g * 256 + n0 + sg_u;
        *(half8*)&Bh[buf][sg_g][sg_u][sg_kq] =
            *(const half8*)&w16[131072 + grow * 256 + ks * 32 + sg_kq];
    };
    stage_b(0, 0);

    // acc init from gq (global f32, scattered)
    const int unit = n0 + m;
    floatx4 acc[4];
    #pragma unroll
    for (int rr = 0; rr < 4; ++rr) {
        const int b = b0 + wv * 16 + quad * 4 + rr;
        #pragma unroll
        for (int g = 0; g < 4; ++g) acc[g][rr] = gqB[(size_t)b * 1024 + g * 256 + unit];
    }
    __syncthreads();

    for (int ks = 0; ks < 8; ++ks) {
        if (ks + 1 < 8) stage_b(ks + 1, (ks + 1) & 1);
        half8 a = *(const half8*)&Ah[(wv * 16 + m) * AWG + ks * 32 + quad * 8];
        #pragma unroll
        for (int g = 0; g < 4; ++g) {
            half8 bf = *(const half8*)&Bh[ks & 1][g][m][quad * 8];
            acc[g] = __builtin_amdgcn_mfma_f32_16x16x32_f16(a, bf, acc[g], 0, 0, 0);
        }
        __syncthreads();
    }

    float bi[4];
    #pragma unroll
    for (int g = 0; g < 4; ++g) bi[g] = b_ih[g * 256 + unit] + b_hh[g * 256 + unit];
    #pragma unroll
    for (int rr = 0; rr < 4; ++rr) {
        const int b = b0 + wv * 16 + quad * 4 + rr;
        float gi = acc[0][rr] + bi[0];
        float gf = acc[1][rr] + bi[1];
        float gg = acc[2][rr] + bi[2];
        float go = acc[3][rr] + bi[3];
        float cold = cbuf[b * 256 + unit];
        float cn = sigmoid_f(gf) * cold + sigmoid_f(gi) * tanh_fast(gg);
        cbuf[b * 256 + unit] = cn;
        if (n0 < D) {
            float ho = qb[b * D + unit] + sigmoid_f(go) * tanh_fast(cn);
            hout[b * D + unit] = ho;
            hHout[b * D + unit] = (_Float16)ho;
        }
    }
}

// ---------------------------------------------------------------------------
// Kernel 5: cosine similarity per row. One wave per row.
// ---------------------------------------------------------------------------
__global__ __launch_bounds__(64) void k_cosine(
    const float* __restrict__ hout, const float* __restrict__ sg,
    float* __restrict__ out)
{
    const int b = blockIdx.x, t = threadIdx.x;
    float a0 = hout[b * D + t], a1 = hout[b * D + t + 64];
    float s0 = sg[b * D + t], s1 = sg[b * D + t + 64];
    float cr = a0 * s0 + a1 * s1;
    float n1 = a0 * a0 + a1 * a1;
    float n2 = s0 * s0 + s1 * s1;
    for (int off = 32; off; off >>= 1) {
        cr += __shfl_down(cr, off);
        n1 += __shfl_down(n1, off);
        n2 += __shfl_down(n2, off);
    }
    if (t == 0) out[b] = cr / sqrtf(n1 * n2);
}

// ---------------------------------------------------------------------------
extern "C" void kernel_launch(void* const* d_in, const int* in_sizes, int n_in,
                              void* d_out, int out_size, void* d_ws, size_t ws_size,
                              hipStream_t stream)
{
    const int*   relations = (const int*)d_in[0];
    const int*   entities  = (const int*)d_in[1];
    const int*   query     = (const int*)d_in[2];
    const float* emb       = (const float*)d_in[3];
    const float* gcn_w     = (const float*)d_in[4];
    const float* gcn_b     = (const float*)d_in[5];
    const float* p1_w      = (const float*)d_in[6];
    const float* p1_b      = (const float*)d_in[7];
    const float* p2_w      = (const float*)d_in[8];
    const float* p2_b      = (const float*)d_in[9];
    const float* ln_a      = (const float*)d_in[10];
    const float* ln_b      = (const float*)d_in[11];
    const float* w_ih      = (const float*)d_in[12];
    const float* w_hh      = (const float*)d_in[13];
    const float* b_ih      = (const float*)d_in[14];
    const float* b_hh      = (const float*)d_in[15];

    // Workspace layout (float-slot offsets)
    float* ws = (float*)d_ws;
    float*     sg   = ws;                          // 131072
    float*     qb   = ws + 131072;                 // 131072
    float*     hoF  = ws + 262144;                 // 131072 (f32 h_out, final use)
    float*     cb   = ws + 393216;                 // 262144
    float*     gqB  = ws + 655360;                 // 1048576 (1024x1024 f32)
    _Float16*  sgH  = (_Float16*)(ws + 1703936);   // 65536 slots each
    _Float16*  sgT  = (_Float16*)(ws + 1769472);
    _Float16*  qbH  = (_Float16*)(ws + 1835008);
    _Float16*  hHA  = (_Float16*)(ws + 1900544);
    _Float16*  hHB  = (_Float16*)(ws + 1966080);
    _Float16*  rH   = (_Float16*)(ws + 2031616);
    _Float16*  w16  = (_Float16*)(ws + 2097152);   // 196608 slots
    // end: 2293760 floats = 9.2 MB

    k_cvtw<<<dim3(192), dim3(256), 0, stream>>>(w_ih, w_hh, w16);
    k_support<<<dim3(B_SZ), dim3(512), 0, stream>>>(
        relations, entities, query, emb, gcn_w, gcn_b,
        p1_w, p1_b, p2_w, p2_b, ln_a, ln_b, sg, sgH, sgT, qb, qbH);

    // step 0: gq + pointwise (c=0) -> hHB
    k_gq<<<dim3(16, 16), dim3(256), 0, stream>>>(
        qbH, w16, b_ih, b_hh, qb, gqB, cb, hoF, hHB);

    // step 1
    k_attn<<<dim3(64), dim3(1024), 0, stream>>>(hHB, sgH, sgT, rH);
    k_gates<<<dim3(16, 16), dim3(256), 0, stream>>>(
        hHB, rH, w16, gqB, b_ih, b_hh, qb, cb, hoF, hHA);
    // step 2
    k_attn<<<dim3(64), dim3(1024), 0, stream>>>(hHA, sgH, sgT, rH);
    k_gates<<<dim3(16, 16), dim3(256), 0, stream>>>(
        hHA, rH, w16, gqB, b_ih, b_hh, qb, cb, hoF, hHB);
    // step 3 (attention of step 3 is dead)
    k_attn<<<dim3(64), dim3(1024), 0, stream>>>(hHB, sgH, sgT, rH);
    k_gates<<<dim3(16, 16), dim3(256), 0, stream>>>(
        hHB, rH, w16, gqB, b_ih, b_hh, qb, cb, hoF, hHA);

    k_cosine<<<dim3(B_SZ), dim3(64), 0, stream>>>(hoF, sg, (float*)d_out);
}